// Round 10
// baseline (3303.552 us; speedup 1.0000x reference)
//
#include <hip/hip_runtime.h>
#include <math.h>

#define Q 2048
#define NOBS 8192

// ---------------------------------------------------------------------------
// readlane broadcast (lane index literal after unroll): VALU->SGPR, no LDS.
__device__ __forceinline__ float rl(float v, int l) {
  return __int_as_float(__builtin_amdgcn_readlane(__float_as_int(v), l));
}

// ---------------------------------------------------------------------------
__device__ __forceinline__ float block_sum256(float v, volatile float* red) {
  int tid = threadIdx.x;
#pragma unroll
  for (int o = 32; o > 0; o >>= 1) v += __shfl_down(v, o);
  __syncthreads();
  if ((tid & 63) == 0) red[tid >> 6] = v;
  __syncthreads();
  return red[0] + red[1] + red[2] + red[3];
}

// ---------------------------------------------------------------------------
// In-register 64x64 Cholesky, one wave, lane = row (round-3/4 proven).
// rr[64] MUST stay in VGPRs (spill = 25x slowdown, measured round 3).
__device__ __forceinline__ float chol64_reg(float rr[64], int lane) {
  float dv = 1.0f;
#pragma unroll
  for (int j = 0; j < 64; ++j) {
    float vjj = rl(rr[j], j);
    float invd = rsqrtf(vjj);
    float lij = rr[j] * invd;   // lane j gets sqrt(vjj)
    rr[j] = lij;
    if (lane == j) dv = lij;
#pragma unroll
    for (int k = j + 1; k < 64; ++k) rr[k] -= lij * rl(lij, k);
  }
  return dv;
}

// ---------------------------------------------------------------------------
// After chol64_reg (lane holds row `lane` of L in rr, myinv = 1/diag):
// computes COLUMN `lane` of W = L^{-1} into wcol via forward substitution.
// wcol[r] = (I[r][lane] - sum_{p<r} L[r][p]*wcol[p]) / L[r][r].
// Serial over r but runs ONCE per step (job0 only) — consumers then use
// X = A*W^T as a plain GEMM instead of a serial triangular solve.
__device__ __forceinline__ void inv64_reg(const float rr[64], float myinv,
                                          float wcol[64], int lane) {
#pragma unroll
  for (int r = 0; r < 64; ++r) {
    float s = (lane == r) ? 1.0f : 0.0f;
#pragma unroll
    for (int p = 0; p < 64; ++p)
      if (p < r) s -= rl(rr[p], r) * wcol[p];
    wcol[r] = s * rl(myinv, r);
  }
}

// ---------------------------------------------------------------------------
__global__ __launch_bounds__(256) void obs_kernel(
    const float* __restrict__ yt, const float* __restrict__ yp,
    const int* __restrict__ zidx, const float* __restrict__ s2e_p,
    const float* __restrict__ s2b_p, float* __restrict__ t,
    int* __restrict__ cnt, float* __restrict__ scal) {
  __shared__ float red[4];
  int i = blockIdx.x * 256 + threadIdx.x;
  float s2e = s2e_p[0], s2b = s2b_p[0];
  float sig2 = s2e + s2b;
  float r = yt[i] - yp[i];
  float e = erff(r * rsqrtf(2.0f * sig2));
  float u = 0.5f * (e + 1.0f);
  u = fminf(fmaxf(u, 1e-5f), 1.0f - 1e-5f);
  float m = erfinvf(2.0f * u - 1.0f) * 1.4142135623730951f;
  float slp = -0.5f * logf(2.0f * 3.14159265358979f * sig2) - r * r / (2.0f * sig2);
  int z = zidx[i];
  atomicAdd(&t[z], m);
  atomicAdd(&cnt[z], 1);
  float s1 = block_sum256(slp, red);
  float s2 = block_sum256(m * m, red);
  if (threadIdx.x == 0) {
    atomicAdd(&scal[0], s1);   // sum_log_pdf
    atomicAdd(&scal[1], s2);   // m'm
  }
}

// ---------------------------------------------------------------------------
// Fused: build G row j AND the matvec w = K t in one pass over dist row j.
__global__ __launch_bounds__(256) void build_mv(
    const float* __restrict__ dist, const float* __restrict__ s2e_p,
    const float* __restrict__ s2b_p, const float* __restrict__ ell_p,
    const int* __restrict__ cnt, const float* __restrict__ t,
    float* __restrict__ G, float* __restrict__ z, float* __restrict__ scal) {
  __shared__ float red[4];
  int j = blockIdx.x;
  float s2e = s2e_p[0], s2b = s2b_p[0], ell = ell_p[0];
  float sig2 = s2e + s2b;
  float ratio = s2b / sig2;
  float diag = s2e / sig2;
  float inv2ell = 1.0f / (2.0f * ell);
  float cj = (float)cnt[j];
  const float* drow = dist + (size_t)j * Q;
  float* grow = G + (size_t)j * Q;
  float s = 0.0f;
  for (int k = threadIdx.x; k < Q; k += 256) {
    float e = expf(-drow[k] * inv2ell);
    s += e * t[k];
    float g = sqrtf(cj * (float)cnt[k]) * (ratio * e);
    if (j == k) g += diag;
    grow[k] = g;
  }
  float tot = block_sum256(s, red);
  if (threadIdx.x == 0) {
    float wj = ratio * tot;
    z[j] = sqrtf(cj) * wj;          // b = W^{1/2} w
    atomicAdd(&scal[2], t[j] * wj); // t.w
  }
}

// ---------------------------------------------------------------------------
// Factor G(0,0), INVERT the factor, store W(0)=L^{-1} column-major into dsA
// (dsA[c*64+r] = W[r][c]); accumulate logdet. Single wave, full VGPR budget.
__global__ __launch_bounds__(64, 1) void potrf_first(
    const float* __restrict__ G, float* __restrict__ dsA,
    float* __restrict__ scal) {
  int lane = threadIdx.x;
  float rr[64];
  const float* row = G + (size_t)lane * Q;
#pragma unroll
  for (int k4 = 0; k4 < 16; ++k4) {
    float4 v = *(const float4*)(row + k4 * 4);
    rr[k4 * 4 + 0] = v.x; rr[k4 * 4 + 1] = v.y;
    rr[k4 * 4 + 2] = v.z; rr[k4 * 4 + 3] = v.w;
  }
  float dv = chol64_reg(rr, lane);
  float lg = logf(dv);
#pragma unroll
  for (int o = 32; o > 0; o >>= 1) lg += __shfl_down(lg, o);
  if (lane == 0) atomicAdd(&scal[3], lg);
  float wcol[64];
  inv64_reg(rr, 1.0f / dv, wcol, lane);
#pragma unroll
  for (int k4 = 0; k4 < 16; ++k4) {
    float4 st;
    st.x = wcol[k4 * 4 + 0]; st.y = wcol[k4 * 4 + 1];
    st.z = wcol[k4 * 4 + 2]; st.w = wcol[k4 * 4 + 3];
    *(float4*)(dsA + lane * 64 + k4 * 4) = st;   // lane = column c of W
  }
}

// ---------------------------------------------------------------------------
// ONE dispatch per Cholesky step s (j0 = s*64). Sync = kernel boundary only
// (r2/r7: in-kernel fences cost more). dsR holds W(s)=L(s)^{-1}: consumers
// form X = A*W^T by GEMM (all 4 waves) — NO serial triangular solves in
// tiles (r9's 20us/estep was the 2-wave solve chains). job0 additionally
// factors+inverts the next diag into dsW (the only serial chains, 1/step).
//   bx == 0 (job0): X=A_{s+1}W^T; D'=G(j1,j1)-XX^T; chol64+inv64 -> dsW;
//                   logdet; z1(s)=W z2(s) -> publish; z(s+1) -= X z1(s).
//   tjob=bx-1 in [1,ntile): tile (bi,bk): X_bi=A_bi W^T, X_bk=A_bk W^T,
//                   G(bi,bk) -= X_bi X_bk^T; sym tiles also update z(bi).
__global__ __launch_bounds__(256, 1) void estep(
    float* __restrict__ G, float* __restrict__ z, float* __restrict__ z1,
    float* __restrict__ scal, const float* __restrict__ dsR,
    float* __restrict__ dsW, int j0) {
  __shared__ __align__(16) float shA[64 * 68];
  __shared__ __align__(16) float shB[64 * 68];
  __shared__ __align__(16) float shW[64 * 68];
  __shared__ float z1s[64];
  __shared__ float z2s[64];
  int tid = threadIdx.x, bx = blockIdx.x;
  int lane = tid & 63, wv = tid >> 6;
  int tx = tid & 15, ty = tid >> 4;
  int j1 = j0 + 64;

  bool isjob0 = (bx == 0);
  int tjob = bx - 1;
  if (!isjob0 && tjob == 0) return;   // (s+1,s+1): job0's tile

  int R0, C0;
  bool sym;
  if (isjob0) {
    R0 = j1; C0 = j1; sym = true;
  } else {
    int bi = (int)((sqrtf(8.0f * (float)tjob + 1.0f) - 1.0f) * 0.5f);
    while ((bi + 1) * (bi + 2) / 2 <= tjob) ++bi;
    while (bi * (bi + 1) / 2 > tjob) --bi;
    int bk = tjob - bi * (bi + 1) / 2;
    R0 = j1 + bi * 64; C0 = j1 + bk * 64; sym = (bi == bk);
  }

  // ---- stage W (shW[c*68+j] = W[j][c]; dsR is column-major already) ----
#pragma unroll
  for (int it = 0; it < 4; ++it) {
    int idx = it * 256 + tid;
    int c = idx >> 4, r4 = (idx & 15) * 4;
    float4 w = *(const float4*)(dsR + c * 64 + r4);
    *(float4*)&shW[c * 68 + r4] = w;
  }
  // ---- stage A^T tiles (G rows, panel col j0) — r4-proven coalesced ----
#pragma unroll
  for (int it = 0; it < 4; ++it) {
    int idx = it * 256 + tid;
    int r = idx >> 4, c4 = (idx & 15) * 4;
    float4 v = *(const float4*)(G + (size_t)(R0 + r) * Q + j0 + c4);
    shA[(c4 + 0) * 68 + r] = v.x; shA[(c4 + 1) * 68 + r] = v.y;
    shA[(c4 + 2) * 68 + r] = v.z; shA[(c4 + 3) * 68 + r] = v.w;
    if (!sym) {
      float4 u = *(const float4*)(G + (size_t)(C0 + r) * Q + j0 + c4);
      shB[(c4 + 0) * 68 + r] = u.x; shB[(c4 + 1) * 68 + r] = u.y;
      shB[(c4 + 2) * 68 + r] = u.z; shB[(c4 + 3) * 68 + r] = u.w;
    }
  }
  if (sym && tid < 64) z2s[tid] = z[j0 + tid];
  __syncthreads();

  // ---- wave1 (sym/job0): z1(s) = W . z2(s) matvec ----
  if (sym && wv == 1) {
    float a = 0.f;
#pragma unroll
    for (int c = 0; c < 64; ++c) a += shW[c * 68 + lane] * z2s[c];
    z1s[lane] = a;
  }

  // ---- GEMM1: X1 = A_bi . W^T  (and X2 = A_bk . W^T if !sym) ----
  float acc1[4][4] = {{0.f}};
  float acc2[4][4] = {{0.f}};
#pragma unroll 8
  for (int c = 0; c < 64; ++c) {
    float4 a4 = *(const float4*)&shA[c * 68 + ty * 4];
    float4 w4 = *(const float4*)&shW[c * 68 + tx * 4];
    float av[4] = {a4.x, a4.y, a4.z, a4.w};
    float wv4[4] = {w4.x, w4.y, w4.z, w4.w};
#pragma unroll
    for (int i = 0; i < 4; ++i)
#pragma unroll
      for (int jj = 0; jj < 4; ++jj) acc1[i][jj] += av[i] * wv4[jj];
    if (!sym) {
      float4 b4 = *(const float4*)&shB[c * 68 + ty * 4];
      float bv[4] = {b4.x, b4.y, b4.z, b4.w};
#pragma unroll
      for (int i = 0; i < 4; ++i)
#pragma unroll
        for (int jj = 0; jj < 4; ++jj) acc2[i][jj] += bv[i] * wv4[jj];
    }
  }
  __syncthreads();

  // ---- write X^T back into shA/shB (shA[j*68+r] = X1[r][j]) ----
#pragma unroll
  for (int jj = 0; jj < 4; ++jj) {
    float4 s1;
    s1.x = acc1[0][jj]; s1.y = acc1[1][jj];
    s1.z = acc1[2][jj]; s1.w = acc1[3][jj];
    *(float4*)&shA[(tx * 4 + jj) * 68 + ty * 4] = s1;
    if (!sym) {
      float4 s2;
      s2.x = acc2[0][jj]; s2.y = acc2[1][jj];
      s2.z = acc2[2][jj]; s2.w = acc2[3][jj];
      *(float4*)&shB[(tx * 4 + jj) * 68 + ty * 4] = s2;
    }
  }
  __syncthreads();

  // ---- GEMM2: acc = X1 . X2^T (sym: X1 . X1^T) ----
  const float* sB2 = sym ? shA : shB;
  float acc[4][4] = {{0.f}};
#pragma unroll 8
  for (int j = 0; j < 64; ++j) {
    float4 a4 = *(const float4*)&shA[j * 68 + ty * 4];
    float4 b4 = *(const float4*)&sB2[j * 68 + tx * 4];
    float av[4] = {a4.x, a4.y, a4.z, a4.w};
    float bv[4] = {b4.x, b4.y, b4.z, b4.w};
#pragma unroll
    for (int i = 0; i < 4; ++i)
#pragma unroll
      for (int jj = 0; jj < 4; ++jj) acc[i][jj] += av[i] * bv[jj];
  }

  if (isjob0) {
    // ---- D' = G(j1,j1) - acc -> shW row-major (shW free after GEMM1) ----
#pragma unroll
    for (int i = 0; i < 4; ++i) {
      const float* gp = G + (size_t)(j1 + ty * 4 + i) * Q + j1 + tx * 4;
      float4 g = *(const float4*)gp;
      shW[(ty * 4 + i) * 68 + tx * 4 + 0] = g.x - acc[i][0];
      shW[(ty * 4 + i) * 68 + tx * 4 + 1] = g.y - acc[i][1];
      shW[(ty * 4 + i) * 68 + tx * 4 + 2] = g.z - acc[i][2];
      shW[(ty * 4 + i) * 68 + tx * 4 + 3] = g.w - acc[i][3];
    }
    __syncthreads();
    if (wv == 1) {
      // z(s+1) -= X . z1(s); publish z1(s)
      float zs = 0.f;
#pragma unroll 8
      for (int j = 0; j < 64; ++j) zs += shA[j * 68 + lane] * z1s[j];
      z[j1 + lane] -= zs;
      z1[j0 + lane] = z1s[lane];
    }
    if (wv == 0) {
      float rr[64];
#pragma unroll
      for (int k4 = 0; k4 < 16; ++k4) {
        float4 v = *(const float4*)&shW[lane * 68 + k4 * 4];
        rr[k4 * 4 + 0] = v.x; rr[k4 * 4 + 1] = v.y;
        rr[k4 * 4 + 2] = v.z; rr[k4 * 4 + 3] = v.w;
      }
      __builtin_amdgcn_s_setprio(1);
      float dv = chol64_reg(rr, lane);
      float lg = logf(dv);
#pragma unroll
      for (int o = 32; o > 0; o >>= 1) lg += __shfl_down(lg, o);
      if (lane == 0) atomicAdd(&scal[3], lg);
      float wcol[64];
      inv64_reg(rr, 1.0f / dv, wcol, lane);
      __builtin_amdgcn_s_setprio(0);
#pragma unroll
      for (int k4 = 0; k4 < 16; ++k4) {
        float4 st;
        st.x = wcol[k4 * 4 + 0]; st.y = wcol[k4 * 4 + 1];
        st.z = wcol[k4 * 4 + 2]; st.w = wcol[k4 * 4 + 3];
        *(float4*)(dsW + lane * 64 + k4 * 4) = st;
      }
    }
    return;
  }

  // ---- tiles: sym wave1 applies the z reduction for its block ----
  if (sym && wv == 1) {
    float zs = 0.f;
#pragma unroll 8
    for (int j = 0; j < 64; ++j) zs += shA[j * 68 + lane] * z1s[j];
    z[R0 + lane] -= zs;
  }
#pragma unroll
  for (int i = 0; i < 4; ++i) {
    float* gp = G + (size_t)(R0 + ty * 4 + i) * Q + C0 + tx * 4;
    float4 g = *(const float4*)gp;
    g.x -= acc[i][0]; g.y -= acc[i][1];
    g.z -= acc[i][2]; g.w -= acc[i][3];
    *(float4*)gp = g;
  }
}

// ---------------------------------------------------------------------------
// z1(31) = W31 . z2(31) (matvec from ds31, column-major), then assemble.
__global__ __launch_bounds__(256) void final_assemble(
    const float* __restrict__ z, const float* __restrict__ z1,
    const float* __restrict__ ds31, const float* __restrict__ scal,
    const float* __restrict__ s2e_p, const float* __restrict__ s2b_p,
    float* __restrict__ out) {
  __shared__ float red[4];
  __shared__ float z1last[64];
  __shared__ float z2l[64];
  int tid = threadIdx.x;
  if (tid < 64) z2l[tid] = z[Q - 64 + tid];
  __syncthreads();
  if (tid < 64) {
    int lane = tid;
    float a = 0.f;
#pragma unroll
    for (int c = 0; c < 64; ++c) a += ds31[c * 64 + lane] * z2l[c];
    z1last[lane] = a;
  }
  __syncthreads();
  float bv = 0.f;
  for (int i = tid; i < Q; i += 256) {
    float zi = (i < Q - 64) ? z1[i] : z1last[i - (Q - 64)];
    bv += zi * zi;
  }
  float bvs = block_sum256(bv, red);
  if (tid == 0) {
    float s2e = s2e_p[0], s2b = s2b_p[0];
    float sig2 = s2e + s2b;
    float c = s2e / sig2;
    float slp = scal[0], mtm = scal[1];
    float tw = scal[2], sl = scal[3];
    float tty = (tw - bvs) / c;          // t' y
    float mrm = (mtm - tty) / c;         // m' R^{-1} m
    float logdetR = (float)(NOBS - Q) * logf(c) + 2.0f * sl;
    out[0] = 0.5f * logdetR + 0.5f * mrm - 0.5f * mtm + 0.5f * slp;
  }
}

// ---------------------------------------------------------------------------
extern "C" void kernel_launch(void* const* d_in, const int* in_sizes, int n_in,
                              void* d_out, int out_size, void* d_ws, size_t ws_size,
                              hipStream_t stream) {
  const float* yt   = (const float*)d_in[0];
  const float* yp   = (const float*)d_in[1];
  const int*   zidx = (const int*)d_in[2];
  const float* dist = (const float*)d_in[3];
  const float* s2e  = (const float*)d_in[4];
  const float* s2b  = (const float*)d_in[5];
  const float* ell  = (const float*)d_in[6];

  float* ws   = (float*)d_ws;
  float* G    = ws;                         // Q*Q floats = 16 MB
  float* z    = ws + (size_t)Q * Q;         // Q (running-reduced z2 values)
  float* t    = z + Q;                      // Q
  int*   cntv = (int*)(t + Q);              // Q ints
  float* scal = t + 2 * Q;                  // 8: slp, mtm, tw, sumlogL
  float* z1   = scal + 8;                   // Q (solved y = L^{-1} b)
  float* dsA  = z1 + Q;                     // 64*64 W = L^{-1} (even s)
  float* dsB  = dsA + 4096;                 // 64*64 W = L^{-1} (odd s)

  // zero t, cntv, scal
  hipMemsetAsync(t, 0, (2 * Q + 8) * sizeof(float), stream);

  obs_kernel<<<NOBS / 256, 256, 0, stream>>>(yt, yp, zidx, s2e, s2b, t, cntv, scal);
  build_mv<<<Q, 256, 0, stream>>>(dist, s2e, s2b, ell, cntv, t, G, z, scal);

  potrf_first<<<1, 64, 0, stream>>>(G, dsA, scal);

  // one dispatch per step: consumers form X = A.W^T by GEMM (no solves)
  for (int s = 0; s <= 30; ++s) {
    int m = 31 - s;
    int ntile = m * (m + 1) / 2;
    const float* dsR = (s & 1) ? dsB : dsA;
    float* dsW = (s & 1) ? dsA : dsB;
    estep<<<1 + ntile, 256, 0, stream>>>(G, z, z1, scal, dsR, dsW, s * 64);
  }

  final_assemble<<<1, 256, 0, stream>>>(z, z1, dsB, scal, s2e, s2b,
                                        (float*)d_out);
}

// Round 11
// 2197.568 us; speedup vs baseline: 1.5033x; 1.5033x over previous
//
#include <hip/hip_runtime.h>
#include <math.h>

#define Q 2048
#define NOBS 8192

// ---------------------------------------------------------------------------
// readlane broadcast (lane index literal after unroll): VALU->SGPR, no LDS.
__device__ __forceinline__ float rl(float v, int l) {
  return __int_as_float(__builtin_amdgcn_readlane(__float_as_int(v), l));
}

// ---------------------------------------------------------------------------
__device__ __forceinline__ float block_sum256(float v, volatile float* red) {
  int tid = threadIdx.x;
#pragma unroll
  for (int o = 32; o > 0; o >>= 1) v += __shfl_down(v, o);
  __syncthreads();
  if ((tid & 63) == 0) red[tid >> 6] = v;
  __syncthreads();
  return red[0] + red[1] + red[2] + red[3];
}

// ---------------------------------------------------------------------------
// In-register 64x64 Cholesky, one wave, lane = row (round-3/4 proven).
// rr[64] MUST stay in VGPRs (spill = 25x slowdown, measured round 3).
__device__ __forceinline__ float chol64_reg(float rr[64], int lane) {
  float dv = 1.0f;
#pragma unroll
  for (int j = 0; j < 64; ++j) {
    float vjj = rl(rr[j], j);
    float invd = rsqrtf(vjj);
    float lij = rr[j] * invd;   // lane j gets sqrt(vjj)
    rr[j] = lij;
    if (lane == j) dv = lij;
#pragma unroll
    for (int k = j + 1; k < 64; ++k) rr[k] -= lij * rl(lij, k);
  }
  return dv;
}

// ---------------------------------------------------------------------------
// W = L^{-1}, lane c holds COLUMN c of W in wcol. SCATTER-FORM forward
// substitution — the EXACT triangular loop shape of chol64_reg (outer p,
// inner r>p, all register indices static). Round-10 lesson: the gather form
// (outer r, inner p<r guarded by if) blew clang's unroll budget inside the
// big estep kernel -> dynamic indexing -> scratch spill -> 117us (VGPR=80).
// This shape compiles like chol64 (proven spill-free since round 4).
__device__ __forceinline__ void inv64_reg(const float rr[64], float myinv,
                                          float wcol[64], int lane) {
#pragma unroll
  for (int r = 0; r < 64; ++r) wcol[r] = (lane == r) ? 1.0f : 0.0f;
#pragma unroll
  for (int p = 0; p < 64; ++p) {
    float wp = wcol[p] * rl(myinv, p);   // w[p] finalized
    wcol[p] = wp;
#pragma unroll
    for (int r = p + 1; r < 64; ++r)
      wcol[r] -= rl(rr[p], r) * wp;      // L[r][p] = readlane(rr[p], r)
  }
}

// ---------------------------------------------------------------------------
__global__ __launch_bounds__(256) void obs_kernel(
    const float* __restrict__ yt, const float* __restrict__ yp,
    const int* __restrict__ zidx, const float* __restrict__ s2e_p,
    const float* __restrict__ s2b_p, float* __restrict__ t,
    int* __restrict__ cnt, float* __restrict__ scal) {
  __shared__ float red[4];
  int i = blockIdx.x * 256 + threadIdx.x;
  float s2e = s2e_p[0], s2b = s2b_p[0];
  float sig2 = s2e + s2b;
  float r = yt[i] - yp[i];
  float e = erff(r * rsqrtf(2.0f * sig2));
  float u = 0.5f * (e + 1.0f);
  u = fminf(fmaxf(u, 1e-5f), 1.0f - 1e-5f);
  float m = erfinvf(2.0f * u - 1.0f) * 1.4142135623730951f;
  float slp = -0.5f * logf(2.0f * 3.14159265358979f * sig2) - r * r / (2.0f * sig2);
  int z = zidx[i];
  atomicAdd(&t[z], m);
  atomicAdd(&cnt[z], 1);
  float s1 = block_sum256(slp, red);
  float s2 = block_sum256(m * m, red);
  if (threadIdx.x == 0) {
    atomicAdd(&scal[0], s1);   // sum_log_pdf
    atomicAdd(&scal[1], s2);   // m'm
  }
}

// ---------------------------------------------------------------------------
// Fused: build G row j AND the matvec w = K t in one pass over dist row j.
__global__ __launch_bounds__(256) void build_mv(
    const float* __restrict__ dist, const float* __restrict__ s2e_p,
    const float* __restrict__ s2b_p, const float* __restrict__ ell_p,
    const int* __restrict__ cnt, const float* __restrict__ t,
    float* __restrict__ G, float* __restrict__ z, float* __restrict__ scal) {
  __shared__ float red[4];
  int j = blockIdx.x;
  float s2e = s2e_p[0], s2b = s2b_p[0], ell = ell_p[0];
  float sig2 = s2e + s2b;
  float ratio = s2b / sig2;
  float diag = s2e / sig2;
  float inv2ell = 1.0f / (2.0f * ell);
  float cj = (float)cnt[j];
  const float* drow = dist + (size_t)j * Q;
  float* grow = G + (size_t)j * Q;
  float s = 0.0f;
  for (int k = threadIdx.x; k < Q; k += 256) {
    float e = expf(-drow[k] * inv2ell);
    s += e * t[k];
    float g = sqrtf(cj * (float)cnt[k]) * (ratio * e);
    if (j == k) g += diag;
    grow[k] = g;
  }
  float tot = block_sum256(s, red);
  if (threadIdx.x == 0) {
    float wj = ratio * tot;
    z[j] = sqrtf(cj) * wj;          // b = W^{1/2} w
    atomicAdd(&scal[2], t[j] * wj); // t.w
  }
}

// ---------------------------------------------------------------------------
// Factor G(0,0), INVERT the factor, store W(0)=L^{-1} column-major into dsA
// (dsA[c*64+r] = W[r][c]); accumulate logdet. Single wave, full VGPR budget.
__global__ __launch_bounds__(64, 1) void potrf_first(
    const float* __restrict__ G, float* __restrict__ dsA,
    float* __restrict__ scal) {
  int lane = threadIdx.x;
  float rr[64];
  const float* row = G + (size_t)lane * Q;
#pragma unroll
  for (int k4 = 0; k4 < 16; ++k4) {
    float4 v = *(const float4*)(row + k4 * 4);
    rr[k4 * 4 + 0] = v.x; rr[k4 * 4 + 1] = v.y;
    rr[k4 * 4 + 2] = v.z; rr[k4 * 4 + 3] = v.w;
  }
  float dv = chol64_reg(rr, lane);
  float lg = logf(dv);
#pragma unroll
  for (int o = 32; o > 0; o >>= 1) lg += __shfl_down(lg, o);
  if (lane == 0) atomicAdd(&scal[3], lg);
  float wcol[64];
  inv64_reg(rr, 1.0f / dv, wcol, lane);
#pragma unroll
  for (int k4 = 0; k4 < 16; ++k4) {
    float4 st;
    st.x = wcol[k4 * 4 + 0]; st.y = wcol[k4 * 4 + 1];
    st.z = wcol[k4 * 4 + 2]; st.w = wcol[k4 * 4 + 3];
    *(float4*)(dsA + lane * 64 + k4 * 4) = st;   // lane = column c of W
  }
}

// ---------------------------------------------------------------------------
// ONE dispatch per Cholesky step s (j0 = s*64). Sync = kernel boundary only
// (r2/r7: in-kernel fences cost more). dsR holds W(s)=L(s)^{-1}: consumers
// form X = A*W^T by GEMM (all 4 waves) — NO serial triangular solves in
// tiles (r9's 20us/estep was the 2-wave solve chains). job0 additionally
// factors+inverts the next diag into dsW (the only serial chains, 1/step).
//   bx == 0 (job0): X=A_{s+1}W^T; D'=G(j1,j1)-XX^T; chol64+inv64 -> dsW;
//                   logdet; z1(s)=W z2(s) -> publish; z(s+1) -= X z1(s).
//   tjob=bx-1 in [1,ntile): tile (bi,bk): X_bi=A_bi W^T, X_bk=A_bk W^T,
//                   G(bi,bk) -= X_bi X_bk^T; sym tiles also update z(bi).
__global__ __launch_bounds__(256, 1) void estep(
    float* __restrict__ G, float* __restrict__ z, float* __restrict__ z1,
    float* __restrict__ scal, const float* __restrict__ dsR,
    float* __restrict__ dsW, int j0) {
  __shared__ __align__(16) float shA[64 * 68];
  __shared__ __align__(16) float shB[64 * 68];
  __shared__ __align__(16) float shW[64 * 68];
  __shared__ float z1s[64];
  __shared__ float z2s[64];
  int tid = threadIdx.x, bx = blockIdx.x;
  int lane = tid & 63, wv = tid >> 6;
  int tx = tid & 15, ty = tid >> 4;
  int j1 = j0 + 64;

  bool isjob0 = (bx == 0);
  int tjob = bx - 1;
  if (!isjob0 && tjob == 0) return;   // (s+1,s+1): job0's tile

  int R0, C0;
  bool sym;
  if (isjob0) {
    R0 = j1; C0 = j1; sym = true;
  } else {
    int bi = (int)((sqrtf(8.0f * (float)tjob + 1.0f) - 1.0f) * 0.5f);
    while ((bi + 1) * (bi + 2) / 2 <= tjob) ++bi;
    while (bi * (bi + 1) / 2 > tjob) --bi;
    int bk = tjob - bi * (bi + 1) / 2;
    R0 = j1 + bi * 64; C0 = j1 + bk * 64; sym = (bi == bk);
  }

  // ---- stage W (shW[c*68+j] = W[j][c]; dsR is column-major already) ----
#pragma unroll
  for (int it = 0; it < 4; ++it) {
    int idx = it * 256 + tid;
    int c = idx >> 4, r4 = (idx & 15) * 4;
    float4 w = *(const float4*)(dsR + c * 64 + r4);
    *(float4*)&shW[c * 68 + r4] = w;
  }
  // ---- stage A^T tiles (G rows, panel col j0) — r4-proven coalesced ----
#pragma unroll
  for (int it = 0; it < 4; ++it) {
    int idx = it * 256 + tid;
    int r = idx >> 4, c4 = (idx & 15) * 4;
    float4 v = *(const float4*)(G + (size_t)(R0 + r) * Q + j0 + c4);
    shA[(c4 + 0) * 68 + r] = v.x; shA[(c4 + 1) * 68 + r] = v.y;
    shA[(c4 + 2) * 68 + r] = v.z; shA[(c4 + 3) * 68 + r] = v.w;
    if (!sym) {
      float4 u = *(const float4*)(G + (size_t)(C0 + r) * Q + j0 + c4);
      shB[(c4 + 0) * 68 + r] = u.x; shB[(c4 + 1) * 68 + r] = u.y;
      shB[(c4 + 2) * 68 + r] = u.z; shB[(c4 + 3) * 68 + r] = u.w;
    }
  }
  if (sym && tid < 64) z2s[tid] = z[j0 + tid];
  __syncthreads();

  // ---- wave1 (sym/job0): z1(s) = W . z2(s) matvec ----
  if (sym && wv == 1) {
    float a = 0.f;
#pragma unroll
    for (int c = 0; c < 64; ++c) a += shW[c * 68 + lane] * z2s[c];
    z1s[lane] = a;
  }

  // ---- GEMM1: X1 = A_bi . W^T  (and X2 = A_bk . W^T if !sym) ----
  float acc1[4][4] = {{0.f}};
  float acc2[4][4] = {{0.f}};
#pragma unroll 8
  for (int c = 0; c < 64; ++c) {
    float4 a4 = *(const float4*)&shA[c * 68 + ty * 4];
    float4 w4 = *(const float4*)&shW[c * 68 + tx * 4];
    float av[4] = {a4.x, a4.y, a4.z, a4.w};
    float wv4[4] = {w4.x, w4.y, w4.z, w4.w};
#pragma unroll
    for (int i = 0; i < 4; ++i)
#pragma unroll
      for (int jj = 0; jj < 4; ++jj) acc1[i][jj] += av[i] * wv4[jj];
    if (!sym) {
      float4 b4 = *(const float4*)&shB[c * 68 + ty * 4];
      float bv[4] = {b4.x, b4.y, b4.z, b4.w};
#pragma unroll
      for (int i = 0; i < 4; ++i)
#pragma unroll
        for (int jj = 0; jj < 4; ++jj) acc2[i][jj] += bv[i] * wv4[jj];
    }
  }
  __syncthreads();

  // ---- write X^T back into shA/shB (shA[j*68+r] = X1[r][j]) ----
#pragma unroll
  for (int jj = 0; jj < 4; ++jj) {
    float4 s1;
    s1.x = acc1[0][jj]; s1.y = acc1[1][jj];
    s1.z = acc1[2][jj]; s1.w = acc1[3][jj];
    *(float4*)&shA[(tx * 4 + jj) * 68 + ty * 4] = s1;
    if (!sym) {
      float4 s2;
      s2.x = acc2[0][jj]; s2.y = acc2[1][jj];
      s2.z = acc2[2][jj]; s2.w = acc2[3][jj];
      *(float4*)&shB[(tx * 4 + jj) * 68 + ty * 4] = s2;
    }
  }
  __syncthreads();

  // ---- GEMM2: acc = X1 . X2^T (sym: X1 . X1^T) ----
  const float* sB2 = sym ? shA : shB;
  float acc[4][4] = {{0.f}};
#pragma unroll 8
  for (int j = 0; j < 64; ++j) {
    float4 a4 = *(const float4*)&shA[j * 68 + ty * 4];
    float4 b4 = *(const float4*)&sB2[j * 68 + tx * 4];
    float av[4] = {a4.x, a4.y, a4.z, a4.w};
    float bv[4] = {b4.x, b4.y, b4.z, b4.w};
#pragma unroll
    for (int i = 0; i < 4; ++i)
#pragma unroll
      for (int jj = 0; jj < 4; ++jj) acc[i][jj] += av[i] * bv[jj];
  }

  if (isjob0) {
    // ---- D' = G(j1,j1) - acc -> shW row-major (shW free after GEMM1) ----
#pragma unroll
    for (int i = 0; i < 4; ++i) {
      const float* gp = G + (size_t)(j1 + ty * 4 + i) * Q + j1 + tx * 4;
      float4 g = *(const float4*)gp;
      shW[(ty * 4 + i) * 68 + tx * 4 + 0] = g.x - acc[i][0];
      shW[(ty * 4 + i) * 68 + tx * 4 + 1] = g.y - acc[i][1];
      shW[(ty * 4 + i) * 68 + tx * 4 + 2] = g.z - acc[i][2];
      shW[(ty * 4 + i) * 68 + tx * 4 + 3] = g.w - acc[i][3];
    }
    __syncthreads();
    if (wv == 1) {
      // z(s+1) -= X . z1(s); publish z1(s)
      float zs = 0.f;
#pragma unroll 8
      for (int j = 0; j < 64; ++j) zs += shA[j * 68 + lane] * z1s[j];
      z[j1 + lane] -= zs;
      z1[j0 + lane] = z1s[lane];
    }
    if (wv == 0) {
      float rr[64];
#pragma unroll
      for (int k4 = 0; k4 < 16; ++k4) {
        float4 v = *(const float4*)&shW[lane * 68 + k4 * 4];
        rr[k4 * 4 + 0] = v.x; rr[k4 * 4 + 1] = v.y;
        rr[k4 * 4 + 2] = v.z; rr[k4 * 4 + 3] = v.w;
      }
      __builtin_amdgcn_s_setprio(1);
      float dv = chol64_reg(rr, lane);
      float lg = logf(dv);
#pragma unroll
      for (int o = 32; o > 0; o >>= 1) lg += __shfl_down(lg, o);
      if (lane == 0) atomicAdd(&scal[3], lg);
      float wcol[64];
      inv64_reg(rr, 1.0f / dv, wcol, lane);
      __builtin_amdgcn_s_setprio(0);
#pragma unroll
      for (int k4 = 0; k4 < 16; ++k4) {
        float4 st;
        st.x = wcol[k4 * 4 + 0]; st.y = wcol[k4 * 4 + 1];
        st.z = wcol[k4 * 4 + 2]; st.w = wcol[k4 * 4 + 3];
        *(float4*)(dsW + lane * 64 + k4 * 4) = st;
      }
    }
    return;
  }

  // ---- tiles: sym wave1 applies the z reduction for its block ----
  if (sym && wv == 1) {
    float zs = 0.f;
#pragma unroll 8
    for (int j = 0; j < 64; ++j) zs += shA[j * 68 + lane] * z1s[j];
    z[R0 + lane] -= zs;
  }
#pragma unroll
  for (int i = 0; i < 4; ++i) {
    float* gp = G + (size_t)(R0 + ty * 4 + i) * Q + C0 + tx * 4;
    float4 g = *(const float4*)gp;
    g.x -= acc[i][0]; g.y -= acc[i][1];
    g.z -= acc[i][2]; g.w -= acc[i][3];
    *(float4*)gp = g;
  }
}

// ---------------------------------------------------------------------------
// z1(31) = W31 . z2(31) (matvec from ds31, column-major), then assemble.
__global__ __launch_bounds__(256) void final_assemble(
    const float* __restrict__ z, const float* __restrict__ z1,
    const float* __restrict__ ds31, const float* __restrict__ scal,
    const float* __restrict__ s2e_p, const float* __restrict__ s2b_p,
    float* __restrict__ out) {
  __shared__ float red[4];
  __shared__ float z1last[64];
  __shared__ float z2l[64];
  int tid = threadIdx.x;
  if (tid < 64) z2l[tid] = z[Q - 64 + tid];
  __syncthreads();
  if (tid < 64) {
    int lane = tid;
    float a = 0.f;
#pragma unroll
    for (int c = 0; c < 64; ++c) a += ds31[c * 64 + lane] * z2l[c];
    z1last[lane] = a;
  }
  __syncthreads();
  float bv = 0.f;
  for (int i = tid; i < Q; i += 256) {
    float zi = (i < Q - 64) ? z1[i] : z1last[i - (Q - 64)];
    bv += zi * zi;
  }
  float bvs = block_sum256(bv, red);
  if (tid == 0) {
    float s2e = s2e_p[0], s2b = s2b_p[0];
    float sig2 = s2e + s2b;
    float c = s2e / sig2;
    float slp = scal[0], mtm = scal[1];
    float tw = scal[2], sl = scal[3];
    float tty = (tw - bvs) / c;          // t' y
    float mrm = (mtm - tty) / c;         // m' R^{-1} m
    float logdetR = (float)(NOBS - Q) * logf(c) + 2.0f * sl;
    out[0] = 0.5f * logdetR + 0.5f * mrm - 0.5f * mtm + 0.5f * slp;
  }
}

// ---------------------------------------------------------------------------
extern "C" void kernel_launch(void* const* d_in, const int* in_sizes, int n_in,
                              void* d_out, int out_size, void* d_ws, size_t ws_size,
                              hipStream_t stream) {
  const float* yt   = (const float*)d_in[0];
  const float* yp   = (const float*)d_in[1];
  const int*   zidx = (const int*)d_in[2];
  const float* dist = (const float*)d_in[3];
  const float* s2e  = (const float*)d_in[4];
  const float* s2b  = (const float*)d_in[5];
  const float* ell  = (const float*)d_in[6];

  float* ws   = (float*)d_ws;
  float* G    = ws;                         // Q*Q floats = 16 MB
  float* z    = ws + (size_t)Q * Q;         // Q (running-reduced z2 values)
  float* t    = z + Q;                      // Q
  int*   cntv = (int*)(t + Q);              // Q ints
  float* scal = t + 2 * Q;                  // 8: slp, mtm, tw, sumlogL
  float* z1   = scal + 8;                   // Q (solved y = L^{-1} b)
  float* dsA  = z1 + Q;                     // 64*64 W = L^{-1} (even s)
  float* dsB  = dsA + 4096;                 // 64*64 W = L^{-1} (odd s)

  // zero t, cntv, scal
  hipMemsetAsync(t, 0, (2 * Q + 8) * sizeof(float), stream);

  obs_kernel<<<NOBS / 256, 256, 0, stream>>>(yt, yp, zidx, s2e, s2b, t, cntv, scal);
  build_mv<<<Q, 256, 0, stream>>>(dist, s2e, s2b, ell, cntv, t, G, z, scal);

  potrf_first<<<1, 64, 0, stream>>>(G, dsA, scal);

  // one dispatch per step: consumers form X = A.W^T by GEMM (no solves)
  for (int s = 0; s <= 30; ++s) {
    int m = 31 - s;
    int ntile = m * (m + 1) / 2;
    const float* dsR = (s & 1) ? dsB : dsA;
    float* dsW = (s & 1) ? dsA : dsB;
    estep<<<1 + ntile, 256, 0, stream>>>(G, z, z1, scal, dsR, dsW, s * 64);
  }

  final_assemble<<<1, 256, 0, stream>>>(z, z1, dsB, scal, s2e, s2b,
                                        (float*)d_out);
}

// Round 12
// 1130.850 us; speedup vs baseline: 2.9213x; 1.9433x over previous
//
#include <hip/hip_runtime.h>
#include <math.h>

#define Q 2048
#define NOBS 8192

// ---------------------------------------------------------------------------
// readlane broadcast (lane index literal after unroll): VALU->SGPR, no LDS.
__device__ __forceinline__ float rl(float v, int l) {
  return __int_as_float(__builtin_amdgcn_readlane(__float_as_int(v), l));
}

// ---------------------------------------------------------------------------
__device__ __forceinline__ float block_sum256(float v, volatile float* red) {
  int tid = threadIdx.x;
#pragma unroll
  for (int o = 32; o > 0; o >>= 1) v += __shfl_down(v, o);
  __syncthreads();
  if ((tid & 63) == 0) red[tid >> 6] = v;
  __syncthreads();
  return red[0] + red[1] + red[2] + red[3];
}

// ---------------------------------------------------------------------------
// In-register 64x64 Cholesky, one wave, lane = row (round-3/4 proven).
// INVARIANT (round 10/11 lesson): at most ONE 64-float register array may be
// live at a time in any kernel — two live arrays (rr+wcol) made the
// allocator spill EVERYTHING (VGPR=76-80, 25x slowdown). r4's syrk_step
// with one array: VGPR=140, no spill.
__device__ __forceinline__ float chol64_reg(float rr[64], int lane) {
  float dv = 1.0f;
#pragma unroll
  for (int j = 0; j < 64; ++j) {
    float vjj = rl(rr[j], j);
    float invd = rsqrtf(vjj);
    float lij = rr[j] * invd;   // lane j gets sqrt(vjj)
    rr[j] = lij;
    if (lane == j) dv = lij;
#pragma unroll
    for (int k = j + 1; k < 64; ++k) rr[k] -= lij * rl(lij, k);
  }
  return dv;
}

// ---------------------------------------------------------------------------
// W = L^{-1}, lane c computes COLUMN c of W in wcol (scatter-form forward
// substitution). L is read from LDS (row-major, stride ldl): L[r][p] is the
// SAME address for all lanes -> broadcast, conflict-free. invDsh[p] = 1/L[p][p].
// This decouples wcol from the chol rr array (one-array invariant).
__device__ __forceinline__ void inv64_lds(const float* Lsh, int ldl,
                                          const float* invDsh,
                                          float wcol[64], int lane) {
#pragma unroll
  for (int r = 0; r < 64; ++r) wcol[r] = (lane == r) ? 1.0f : 0.0f;
#pragma unroll
  for (int p = 0; p < 64; ++p) {
    float wp = wcol[p] * invDsh[p];
    wcol[p] = wp;
#pragma unroll
    for (int r = p + 1; r < 64; ++r)
      wcol[r] -= Lsh[r * ldl + p] * wp;
  }
}

// ---------------------------------------------------------------------------
__global__ __launch_bounds__(256) void obs_kernel(
    const float* __restrict__ yt, const float* __restrict__ yp,
    const int* __restrict__ zidx, const float* __restrict__ s2e_p,
    const float* __restrict__ s2b_p, float* __restrict__ t,
    int* __restrict__ cnt, float* __restrict__ scal) {
  __shared__ float red[4];
  int i = blockIdx.x * 256 + threadIdx.x;
  float s2e = s2e_p[0], s2b = s2b_p[0];
  float sig2 = s2e + s2b;
  float r = yt[i] - yp[i];
  float e = erff(r * rsqrtf(2.0f * sig2));
  float u = 0.5f * (e + 1.0f);
  u = fminf(fmaxf(u, 1e-5f), 1.0f - 1e-5f);
  float m = erfinvf(2.0f * u - 1.0f) * 1.4142135623730951f;
  float slp = -0.5f * logf(2.0f * 3.14159265358979f * sig2) - r * r / (2.0f * sig2);
  int z = zidx[i];
  atomicAdd(&t[z], m);
  atomicAdd(&cnt[z], 1);
  float s1 = block_sum256(slp, red);
  float s2 = block_sum256(m * m, red);
  if (threadIdx.x == 0) {
    atomicAdd(&scal[0], s1);   // sum_log_pdf
    atomicAdd(&scal[1], s2);   // m'm
  }
}

// ---------------------------------------------------------------------------
// Fused: build G row j AND the matvec w = K t in one pass over dist row j.
__global__ __launch_bounds__(256) void build_mv(
    const float* __restrict__ dist, const float* __restrict__ s2e_p,
    const float* __restrict__ s2b_p, const float* __restrict__ ell_p,
    const int* __restrict__ cnt, const float* __restrict__ t,
    float* __restrict__ G, float* __restrict__ z, float* __restrict__ scal) {
  __shared__ float red[4];
  int j = blockIdx.x;
  float s2e = s2e_p[0], s2b = s2b_p[0], ell = ell_p[0];
  float sig2 = s2e + s2b;
  float ratio = s2b / sig2;
  float diag = s2e / sig2;
  float inv2ell = 1.0f / (2.0f * ell);
  float cj = (float)cnt[j];
  const float* drow = dist + (size_t)j * Q;
  float* grow = G + (size_t)j * Q;
  float s = 0.0f;
  for (int k = threadIdx.x; k < Q; k += 256) {
    float e = expf(-drow[k] * inv2ell);
    s += e * t[k];
    float g = sqrtf(cj * (float)cnt[k]) * (ratio * e);
    if (j == k) g += diag;
    grow[k] = g;
  }
  float tot = block_sum256(s, red);
  if (threadIdx.x == 0) {
    float wj = ratio * tot;
    z[j] = sqrtf(cj) * wj;          // b = W^{1/2} w
    atomicAdd(&scal[2], t[j] * wj); // t.w
  }
}

// ---------------------------------------------------------------------------
// Factor G(0,0), invert the factor via LDS-L (one-array invariant), store
// W(0)=L^{-1} column-major into dsA; accumulate logdet. Single wave.
__global__ __launch_bounds__(64, 1) void potrf_first(
    const float* __restrict__ G, float* __restrict__ dsA,
    float* __restrict__ scal) {
  __shared__ float Lsh[64 * 65];
  __shared__ float invDsh[64];
  int lane = threadIdx.x;
  {
    float rr[64];
    const float* row = G + (size_t)lane * Q;
#pragma unroll
    for (int k4 = 0; k4 < 16; ++k4) {
      float4 v = *(const float4*)(row + k4 * 4);
      rr[k4 * 4 + 0] = v.x; rr[k4 * 4 + 1] = v.y;
      rr[k4 * 4 + 2] = v.z; rr[k4 * 4 + 3] = v.w;
    }
    float dv = chol64_reg(rr, lane);
    float lg = logf(dv);
#pragma unroll
    for (int o = 32; o > 0; o >>= 1) lg += __shfl_down(lg, o);
    if (lane == 0) atomicAdd(&scal[3], lg);
    invDsh[lane] = 1.0f / dv;
#pragma unroll
    for (int k = 0; k < 64; ++k) Lsh[lane * 65 + k] = rr[k];
  }
  {
    float wcol[64];
    inv64_lds(Lsh, 65, invDsh, wcol, lane);
#pragma unroll
    for (int k4 = 0; k4 < 16; ++k4) {
      float4 st;
      st.x = wcol[k4 * 4 + 0]; st.y = wcol[k4 * 4 + 1];
      st.z = wcol[k4 * 4 + 2]; st.w = wcol[k4 * 4 + 3];
      *(float4*)(dsA + lane * 64 + k4 * 4) = st;   // lane = column c of W
    }
  }
}

// ---------------------------------------------------------------------------
// ONE dispatch per Cholesky step s (j0 = s*64). Sync = kernel boundary only
// (r2/r7: in-kernel fences cost more). dsR holds W(s)=L(s)^{-1}: consumers
// form X = A*W^T by GEMM (all 4 waves) — no serial triangular solves in
// tiles. job0's chol+inv are the only serial chains (1/step), and they obey
// the one-array invariant (chol rr -> L into LDS -> inv wcol from LDS).
//   bx == 0 (job0): X=A_{s+1}W^T; D'=G(j1,j1)-XX^T; chol64 -> L in LDS ->
//                   inv -> dsW; logdet; z1(s)=W z2(s) -> publish;
//                   z(s+1) -= X z1(s).
//   tjob=bx-1 in [1,ntile): tile (bi,bk): X_bi=A_bi W^T, X_bk=A_bk W^T,
//                   G(bi,bk) -= X_bi X_bk^T; sym tiles also update z(bi).
__global__ __launch_bounds__(256, 1) void estep(
    float* __restrict__ G, float* __restrict__ z, float* __restrict__ z1,
    float* __restrict__ scal, const float* __restrict__ dsR,
    float* __restrict__ dsW, int j0) {
  __shared__ __align__(16) float shA[64 * 68];
  __shared__ __align__(16) float shB[64 * 68];
  __shared__ __align__(16) float shW[64 * 68];
  __shared__ float invDsh[64];
  __shared__ float z1s[64];
  __shared__ float z2s[64];
  int tid = threadIdx.x, bx = blockIdx.x;
  int lane = tid & 63, wv = tid >> 6;
  int tx = tid & 15, ty = tid >> 4;
  int j1 = j0 + 64;

  bool isjob0 = (bx == 0);
  int tjob = bx - 1;
  if (!isjob0 && tjob == 0) return;   // (s+1,s+1): job0's tile

  int R0, C0;
  bool sym;
  if (isjob0) {
    R0 = j1; C0 = j1; sym = true;
  } else {
    int bi = (int)((sqrtf(8.0f * (float)tjob + 1.0f) - 1.0f) * 0.5f);
    while ((bi + 1) * (bi + 2) / 2 <= tjob) ++bi;
    while (bi * (bi + 1) / 2 > tjob) --bi;
    int bk = tjob - bi * (bi + 1) / 2;
    R0 = j1 + bi * 64; C0 = j1 + bk * 64; sym = (bi == bk);
  }

  // ---- stage W (shW[c*68+j] = W[j][c]; dsR is column-major already) ----
#pragma unroll
  for (int it = 0; it < 4; ++it) {
    int idx = it * 256 + tid;
    int c = idx >> 4, r4 = (idx & 15) * 4;
    float4 w = *(const float4*)(dsR + c * 64 + r4);
    *(float4*)&shW[c * 68 + r4] = w;
  }
  // ---- stage A^T tiles (G rows, panel col j0) — r4-proven coalesced ----
#pragma unroll
  for (int it = 0; it < 4; ++it) {
    int idx = it * 256 + tid;
    int r = idx >> 4, c4 = (idx & 15) * 4;
    float4 v = *(const float4*)(G + (size_t)(R0 + r) * Q + j0 + c4);
    shA[(c4 + 0) * 68 + r] = v.x; shA[(c4 + 1) * 68 + r] = v.y;
    shA[(c4 + 2) * 68 + r] = v.z; shA[(c4 + 3) * 68 + r] = v.w;
    if (!sym) {
      float4 u = *(const float4*)(G + (size_t)(C0 + r) * Q + j0 + c4);
      shB[(c4 + 0) * 68 + r] = u.x; shB[(c4 + 1) * 68 + r] = u.y;
      shB[(c4 + 2) * 68 + r] = u.z; shB[(c4 + 3) * 68 + r] = u.w;
    }
  }
  if (sym && tid < 64) z2s[tid] = z[j0 + tid];
  __syncthreads();

  // ---- wave1 (sym/job0): z1(s) = W . z2(s) matvec ----
  if (sym && wv == 1) {
    float a = 0.f;
#pragma unroll
    for (int c = 0; c < 64; ++c) a += shW[c * 68 + lane] * z2s[c];
    z1s[lane] = a;
  }

  // ---- GEMM1: X1 = A_bi . W^T  (and X2 = A_bk . W^T if !sym) ----
  float acc1[4][4] = {{0.f}};
  float acc2[4][4] = {{0.f}};
#pragma unroll 8
  for (int c = 0; c < 64; ++c) {
    float4 a4 = *(const float4*)&shA[c * 68 + ty * 4];
    float4 w4 = *(const float4*)&shW[c * 68 + tx * 4];
    float av[4] = {a4.x, a4.y, a4.z, a4.w};
    float wv4[4] = {w4.x, w4.y, w4.z, w4.w};
#pragma unroll
    for (int i = 0; i < 4; ++i)
#pragma unroll
      for (int jj = 0; jj < 4; ++jj) acc1[i][jj] += av[i] * wv4[jj];
    if (!sym) {
      float4 b4 = *(const float4*)&shB[c * 68 + ty * 4];
      float bv[4] = {b4.x, b4.y, b4.z, b4.w};
#pragma unroll
      for (int i = 0; i < 4; ++i)
#pragma unroll
        for (int jj = 0; jj < 4; ++jj) acc2[i][jj] += bv[i] * wv4[jj];
    }
  }
  __syncthreads();

  // ---- write X^T back into shA/shB (shA[j*68+r] = X1[r][j]) ----
#pragma unroll
  for (int jj = 0; jj < 4; ++jj) {
    float4 s1;
    s1.x = acc1[0][jj]; s1.y = acc1[1][jj];
    s1.z = acc1[2][jj]; s1.w = acc1[3][jj];
    *(float4*)&shA[(tx * 4 + jj) * 68 + ty * 4] = s1;
    if (!sym) {
      float4 s2;
      s2.x = acc2[0][jj]; s2.y = acc2[1][jj];
      s2.z = acc2[2][jj]; s2.w = acc2[3][jj];
      *(float4*)&shB[(tx * 4 + jj) * 68 + ty * 4] = s2;
    }
  }
  __syncthreads();

  // ---- GEMM2: acc = X1 . X2^T (sym: X1 . X1^T) ----
  const float* sB2 = sym ? shA : shB;
  float acc[4][4] = {{0.f}};
#pragma unroll 8
  for (int j = 0; j < 64; ++j) {
    float4 a4 = *(const float4*)&shA[j * 68 + ty * 4];
    float4 b4 = *(const float4*)&sB2[j * 68 + tx * 4];
    float av[4] = {a4.x, a4.y, a4.z, a4.w};
    float bv[4] = {b4.x, b4.y, b4.z, b4.w};
#pragma unroll
    for (int i = 0; i < 4; ++i)
#pragma unroll
      for (int jj = 0; jj < 4; ++jj) acc[i][jj] += av[i] * bv[jj];
  }

  if (isjob0) {
    // ---- D' = G(j1,j1) - acc -> shW row-major (shW free after GEMM1) ----
#pragma unroll
    for (int i = 0; i < 4; ++i) {
      const float* gp = G + (size_t)(j1 + ty * 4 + i) * Q + j1 + tx * 4;
      float4 g = *(const float4*)gp;
      shW[(ty * 4 + i) * 68 + tx * 4 + 0] = g.x - acc[i][0];
      shW[(ty * 4 + i) * 68 + tx * 4 + 1] = g.y - acc[i][1];
      shW[(ty * 4 + i) * 68 + tx * 4 + 2] = g.z - acc[i][2];
      shW[(ty * 4 + i) * 68 + tx * 4 + 3] = g.w - acc[i][3];
    }
    __syncthreads();
    if (wv == 1) {
      // z(s+1) -= X . z1(s); publish z1(s)
      float zs = 0.f;
#pragma unroll 8
      for (int j = 0; j < 64; ++j) zs += shA[j * 68 + lane] * z1s[j];
      z[j1 + lane] -= zs;
      z1[j0 + lane] = z1s[lane];
    }
    if (wv == 0) {
      __builtin_amdgcn_s_setprio(1);
      {   // scoped: rr is the ONLY live 64-array
        float rr[64];
#pragma unroll
        for (int k4 = 0; k4 < 16; ++k4) {
          float4 v = *(const float4*)&shW[lane * 68 + k4 * 4];
          rr[k4 * 4 + 0] = v.x; rr[k4 * 4 + 1] = v.y;
          rr[k4 * 4 + 2] = v.z; rr[k4 * 4 + 3] = v.w;
        }
        float dv = chol64_reg(rr, lane);
        float lg = logf(dv);
#pragma unroll
        for (int o = 32; o > 0; o >>= 1) lg += __shfl_down(lg, o);
        if (lane == 0) atomicAdd(&scal[3], lg);
        invDsh[lane] = 1.0f / dv;
        // L -> shW row-major (D' dead); upper-triangle garbage never read
#pragma unroll
        for (int k = 0; k < 64; ++k) shW[lane * 68 + k] = rr[k];
      }
      {   // scoped: wcol is the ONLY live 64-array; L comes from LDS
        float wcol[64];
        inv64_lds(shW, 68, invDsh, wcol, lane);
#pragma unroll
        for (int k4 = 0; k4 < 16; ++k4) {
          float4 st;
          st.x = wcol[k4 * 4 + 0]; st.y = wcol[k4 * 4 + 1];
          st.z = wcol[k4 * 4 + 2]; st.w = wcol[k4 * 4 + 3];
          *(float4*)(dsW + lane * 64 + k4 * 4) = st;
        }
      }
      __builtin_amdgcn_s_setprio(0);
    }
    return;
  }

  // ---- tiles: sym wave1 applies the z reduction for its block ----
  if (sym && wv == 1) {
    float zs = 0.f;
#pragma unroll 8
    for (int j = 0; j < 64; ++j) zs += shA[j * 68 + lane] * z1s[j];
    z[R0 + lane] -= zs;
  }
#pragma unroll
  for (int i = 0; i < 4; ++i) {
    float* gp = G + (size_t)(R0 + ty * 4 + i) * Q + C0 + tx * 4;
    float4 g = *(const float4*)gp;
    g.x -= acc[i][0]; g.y -= acc[i][1];
    g.z -= acc[i][2]; g.w -= acc[i][3];
    *(float4*)gp = g;
  }
}

// ---------------------------------------------------------------------------
// z1(31) = W31 . z2(31) (matvec from ds31, column-major), then assemble.
__global__ __launch_bounds__(256) void final_assemble(
    const float* __restrict__ z, const float* __restrict__ z1,
    const float* __restrict__ ds31, const float* __restrict__ scal,
    const float* __restrict__ s2e_p, const float* __restrict__ s2b_p,
    float* __restrict__ out) {
  __shared__ float red[4];
  __shared__ float z1last[64];
  __shared__ float z2l[64];
  int tid = threadIdx.x;
  if (tid < 64) z2l[tid] = z[Q - 64 + tid];
  __syncthreads();
  if (tid < 64) {
    int lane = tid;
    float a = 0.f;
#pragma unroll
    for (int c = 0; c < 64; ++c) a += ds31[c * 64 + lane] * z2l[c];
    z1last[lane] = a;
  }
  __syncthreads();
  float bv = 0.f;
  for (int i = tid; i < Q; i += 256) {
    float zi = (i < Q - 64) ? z1[i] : z1last[i - (Q - 64)];
    bv += zi * zi;
  }
  float bvs = block_sum256(bv, red);
  if (tid == 0) {
    float s2e = s2e_p[0], s2b = s2b_p[0];
    float sig2 = s2e + s2b;
    float c = s2e / sig2;
    float slp = scal[0], mtm = scal[1];
    float tw = scal[2], sl = scal[3];
    float tty = (tw - bvs) / c;          // t' y
    float mrm = (mtm - tty) / c;         // m' R^{-1} m
    float logdetR = (float)(NOBS - Q) * logf(c) + 2.0f * sl;
    out[0] = 0.5f * logdetR + 0.5f * mrm - 0.5f * mtm + 0.5f * slp;
  }
}

// ---------------------------------------------------------------------------
extern "C" void kernel_launch(void* const* d_in, const int* in_sizes, int n_in,
                              void* d_out, int out_size, void* d_ws, size_t ws_size,
                              hipStream_t stream) {
  const float* yt   = (const float*)d_in[0];
  const float* yp   = (const float*)d_in[1];
  const int*   zidx = (const int*)d_in[2];
  const float* dist = (const float*)d_in[3];
  const float* s2e  = (const float*)d_in[4];
  const float* s2b  = (const float*)d_in[5];
  const float* ell  = (const float*)d_in[6];

  float* ws   = (float*)d_ws;
  float* G    = ws;                         // Q*Q floats = 16 MB
  float* z    = ws + (size_t)Q * Q;         // Q (running-reduced z2 values)
  float* t    = z + Q;                      // Q
  int*   cntv = (int*)(t + Q);              // Q ints
  float* scal = t + 2 * Q;                  // 8: slp, mtm, tw, sumlogL
  float* z1   = scal + 8;                   // Q (solved y = L^{-1} b)
  float* dsA  = z1 + Q;                     // 64*64 W = L^{-1} (even s)
  float* dsB  = dsA + 4096;                 // 64*64 W = L^{-1} (odd s)

  // zero t, cntv, scal
  hipMemsetAsync(t, 0, (2 * Q + 8) * sizeof(float), stream);

  obs_kernel<<<NOBS / 256, 256, 0, stream>>>(yt, yp, zidx, s2e, s2b, t, cntv, scal);
  build_mv<<<Q, 256, 0, stream>>>(dist, s2e, s2b, ell, cntv, t, G, z, scal);

  potrf_first<<<1, 64, 0, stream>>>(G, dsA, scal);

  // one dispatch per step: consumers form X = A.W^T by GEMM (no solves)
  for (int s = 0; s <= 30; ++s) {
    int m = 31 - s;
    int ntile = m * (m + 1) / 2;
    const float* dsR = (s & 1) ? dsB : dsA;
    float* dsW = (s & 1) ? dsA : dsB;
    estep<<<1 + ntile, 256, 0, stream>>>(G, z, z1, scal, dsR, dsW, s * 64);
  }

  final_assemble<<<1, 256, 0, stream>>>(z, z1, dsB, scal, s2e, s2b,
                                        (float*)d_out);
}